// Round 2
// baseline (116.802 us; speedup 1.0000x reference)
//
#include <hip/hip_runtime.h>

// PatchIoULoss: reference reduces to the single 64x64 top-left patch
// (range(0,16,64)->[0], range(0,1,64)->[0]) of each of 16 fp32 (1,1024,1024)
// images. Per batch b: iand = sum(p*t), ior = sum(p)+sum(t)-iand over the
// patch; out = sum_b (1 - iand/ior). Useful traffic: 512 KB total.
//
// Single fused kernel: block b (of 16) reduces its patch, publishes term to
// ws with a release flag; block 0 acquire-spins on all 16 flags and writes
// the scalar. Sentinel != 0xAAAAAAAA poison and != 0, so it is reset by the
// harness re-poison before every replay.

#define HW_   (1024 * 1024)
#define WROW  1024
#define NB_   16
#define SENT  0x5A5A5A5Au

__global__ __launch_bounds__(1024)
void patch_iou_fused(const float* __restrict__ pred,
                     const float* __restrict__ targ,
                     unsigned int* __restrict__ ws,   // [0..15] term bits, [16..31] flags
                     float* __restrict__ out) {
    const int b = blockIdx.x;        // batch 0..15
    const int t = threadIdx.x;       // 0..1023

    // 1024 threads cover 64 rows x 16 float4-cols
    const int row  = t >> 4;
    const int col4 = t & 15;
    const size_t base = (size_t)b * HW_ + (size_t)row * WROW + (size_t)(col4 << 2);

    const float4 p  = *(const float4*)(pred + base);
    const float4 tg = *(const float4*)(targ + base);

    float sp  = p.x + p.y + p.z + p.w;
    float st  = tg.x + tg.y + tg.z + tg.w;
    float spt = p.x * tg.x + p.y * tg.y + p.z * tg.z + p.w * tg.w;

    // 64-lane wave shuffle reduce
    #pragma unroll
    for (int off = 32; off > 0; off >>= 1) {
        sp  += __shfl_down(sp,  off, 64);
        st  += __shfl_down(st,  off, 64);
        spt += __shfl_down(spt, off, 64);
    }

    __shared__ float red[3][16];
    const int wave = t >> 6;
    const int lane = t & 63;
    if (lane == 0) {
        red[0][wave] = sp;
        red[1][wave] = st;
        red[2][wave] = spt;
    }
    __syncthreads();

    // wave 0 reduces the 16 per-wave partials and publishes the term
    if (wave == 0) {
        float a = (lane < 16) ? red[0][lane] : 0.0f;
        float c = (lane < 16) ? red[1][lane] : 0.0f;
        float d = (lane < 16) ? red[2][lane] : 0.0f;
        #pragma unroll
        for (int off = 8; off > 0; off >>= 1) {
            a += __shfl_down(a, off, 64);
            c += __shfl_down(c, off, 64);
            d += __shfl_down(d, off, 64);
        }
        if (lane == 0) {
            const float ior  = a + c - d;
            const float term = 1.0f - d / ior;
            unsigned int bits = __float_as_uint(term);
            __hip_atomic_store(&ws[b], bits, __ATOMIC_RELAXED, __HIP_MEMORY_SCOPE_AGENT);
            __hip_atomic_store(&ws[NB_ + b], SENT, __ATOMIC_RELEASE, __HIP_MEMORY_SCOPE_AGENT);
        }
    }

    // block 0, lanes 0..15: gather all 16 terms, reduce, store scalar
    if (b == 0 && t < NB_) {
        while (__hip_atomic_load(&ws[NB_ + t], __ATOMIC_ACQUIRE, __HIP_MEMORY_SCOPE_AGENT) != SENT) {
        }
        float term = __uint_as_float(
            __hip_atomic_load(&ws[t], __ATOMIC_RELAXED, __HIP_MEMORY_SCOPE_AGENT));
        #pragma unroll
        for (int off = 8; off > 0; off >>= 1) {
            term += __shfl_down(term, off, 64);
        }
        if (t == 0) out[0] = term;
    }
}

extern "C" void kernel_launch(void* const* d_in, const int* in_sizes, int n_in,
                              void* d_out, int out_size, void* d_ws, size_t ws_size,
                              hipStream_t stream) {
    const float* pred = (const float*)d_in[0];
    const float* targ = (const float*)d_in[1];
    patch_iou_fused<<<NB_, 1024, 0, stream>>>(pred, targ, (unsigned int*)d_ws,
                                              (float*)d_out);
}